// Round 5
// baseline (861.160 us; speedup 1.0000x reference)
//
#include <hip/hip_runtime.h>
#include <hip/hip_bf16.h>

#define B_SZ 4096
#define N_SZ 200

// workspace offsets (4-byte units)
#define OFF_BFRAG 0        // 12288 u32: B-fragments, 3 layers x 2kt x 4ct x 2(hi/lo) x 64 lanes x 4 u32
#define OFF_AW1BT 12288    // 4096 f32: aw1bT[d][k] = att_w1[k][64+d]  (for qc prep)
#define OFF_ERC   16384    // 384  f32: erc[r][k]
#define OFF_QC    16768    // B*64 f32: qc[b][k]

typedef __attribute__((ext_vector_type(8))) __bf16 bf16x8;
typedef __attribute__((ext_vector_type(4))) __bf16 bf16x4;
typedef __attribute__((ext_vector_type(4))) float f32x4;
typedef __attribute__((ext_vector_type(4))) unsigned u32x4;

__device__ __forceinline__ void split2(float x, unsigned &hi, unsigned &lo) {
    unsigned u = __float_as_uint(x);
    hi = (u + 0x7FFFu + ((u >> 16) & 1u)) >> 16;
    float r = x - __uint_as_float(hi << 16);
    unsigned ul = __float_as_uint(r);
    lo = (ul + 0x7FFFu + ((ul >> 16) & 1u)) >> 16;
}

// ---------- prep ----------
__global__ void prep1(const float* __restrict__ gu_w1, const float* __restrict__ gu_b1,
                      const float* __restrict__ gu_w2, const float* __restrict__ att_w1,
                      const float* __restrict__ rate_emb, float* __restrict__ ws) {
    int t = threadIdx.x;  // 1 block x 256
    unsigned* wsu = (unsigned*)ws;
    for (int i = t; i < 12288; i += 256) {
        int frag = i >> 8, within = i & 255, lane = within >> 2, r = within & 3;
        int hl = frag & 1, ct = (frag >> 1) & 3, kt = (frag >> 3) & 1, layer = frag >> 4;
        int col = ct * 16 + (lane & 15);
        int d0 = kt * 32 + 8 * (lane >> 4) + 2 * r;
        float w0, w1v;
        if (layer == 0)      { w0 = gu_w1[col * 128 + d0];  w1v = gu_w1[col * 128 + d0 + 1]; }
        else if (layer == 1) { w0 = gu_w2[col * 64 + d0];   w1v = gu_w2[col * 64 + d0 + 1]; }
        else                 { w0 = att_w1[col * 128 + d0]; w1v = att_w1[col * 128 + d0 + 1]; }
        unsigned h0, l0, h1, l1;
        split2(w0, h0, l0); split2(w1v, h1, l1);
        unsigned lo16 = hl ? l0 : h0;
        unsigned hi16 = hl ? l1 : h1;
        wsu[OFF_BFRAG + i] = lo16 | (hi16 << 16);
    }
    for (int i = t; i < 4096; i += 256) {
        int d = i >> 6, k = i & 63;
        ws[OFF_AW1BT + i] = att_w1[k * 128 + 64 + d];
    }
    for (int i = t; i < 384; i += 256) {
        int rr = i >> 6, k = i & 63;
        float a = gu_b1[k];
        for (int d = 0; d < 64; ++d)
            a += gu_w1[k * 128 + 64 + d] * rate_emb[rr * 64 + d];
        ws[OFF_ERC + i] = a;
    }
}

__global__ void prep2_qc(const int* __restrict__ iids, const float* __restrict__ item_emb,
                         const float* __restrict__ ws, float* __restrict__ qc) {
    int b = blockIdx.x, k = threadIdx.x;
    int iid = iids[b];
    const float* awbT = ws + OFF_AW1BT;
    const float* irow = item_emb + (size_t)iid * 64;
    float acc = 0.f;
    for (int d = 0; d < 64; ++d)
        acc = fmaf(awbT[d * 64 + k], irow[d], acc);
    qc[b * 64 + k] = acc;
}

// ---------- fused main (2-chunk row processing, 4 blocks/CU target) ----------
__global__ __launch_bounds__(256, 4) void fused_main(
    const int* __restrict__ pad, const float* __restrict__ user_emb,
    const float* __restrict__ gu_b2, const float* __restrict__ att_b1,
    const float* __restrict__ att_w2, const float* __restrict__ att_b2,
    const float* __restrict__ agg_w, const float* __restrict__ agg_b,
    const float* __restrict__ ws, float* __restrict__ out) {

    // hi/lo activation planes: 112 local rows x 64 cols bf16 (one chunk).
    // 16B granule g (8 cols) of local row n stored at granule (g ^ (n&7)).
    __shared__ __align__(16) __bf16 XH[112 * 64];
    __shared__ __align__(16) __bf16 XL[112 * 64];
    __shared__ float erc_s[6 * 65];
    __shared__ int   rid_s[112];
    __shared__ float mask_s[112];
    __shared__ float b2_s[64], aw2_s[64], ab1_s[64], qc_s[64];
    __shared__ float aggp[4][64];
    __shared__ float agg_s[64];
    __shared__ float red_s[4];

    const int b = blockIdx.x;
    const int tid = threadIdx.x;
    const int w = tid >> 6;
    const int lane = tid & 63;
    const int lrow = lane & 15;
    const int lgrp = lane >> 4;
    const int lcol = lane & 15;
    const unsigned* __restrict__ bfrag = (const unsigned*)ws + OFF_BFRAG;
    const float ab2 = att_b2[0];

    // one-time tiny staging (covered by chunk-0's stage barrier)
    if (tid < 64) {
        b2_s[tid]  = gu_b2[tid];
        aw2_s[tid] = att_w2[tid];
        ab1_s[tid] = att_b1[tid];
        qc_s[tid]  = ws[OFF_QC + b * 64 + tid];
    }
    for (int i = tid; i < 384; i += 256)
        erc_s[(i >> 6) * 65 + (i & 63)] = ws[OFF_ERC + i];

    // A-frag: local row ln = lt*16+lrow, k = kt*32+8*lgrp+e -> one swizzled granule
    auto loadA = [&](const __bf16* P, int lt, bf16x8 A[2]) {
        int ln = lt * 16 + lrow;
        int s = ln & 7;
#pragma unroll
        for (int kt = 0; kt < 2; ++kt)
            A[kt] = *(const bf16x8*)&P[ln * 64 + (((kt * 4 + lgrp) ^ s) << 3)];
    };

#define LOAD_B(LAYER)                                                            \
    u32x4 bh[4][2], bl[4][2];                                                    \
    _Pragma("unroll")                                                            \
    for (int ct = 0; ct < 4; ++ct)                                               \
        _Pragma("unroll")                                                        \
        for (int kt = 0; kt < 2; ++kt) {                                         \
            int fb = (((LAYER) * 2 + kt) * 4 + ct) * 2;                          \
            bh[ct][kt] = *(const u32x4*)&bfrag[(fb + 0) * 256 + lane * 4];       \
            bl[ct][kt] = *(const u32x4*)&bfrag[(fb + 1) * 256 + lane * 4];       \
        }

#define MFMA3(ACC)                                                               \
    _Pragma("unroll")                                                            \
    for (int ct = 0; ct < 4; ++ct)                                               \
        _Pragma("unroll")                                                        \
        for (int kt = 0; kt < 2; ++kt) {                                         \
            bf16x8 BH = __builtin_bit_cast(bf16x8, bh[ct][kt]);                  \
            bf16x8 BL = __builtin_bit_cast(bf16x8, bl[ct][kt]);                  \
            ACC[ct] = __builtin_amdgcn_mfma_f32_16x16x32_bf16(AL[kt], BH, ACC[ct], 0, 0, 0); \
            ACC[ct] = __builtin_amdgcn_mfma_f32_16x16x32_bf16(AH[kt], BL, ACC[ct], 0, 0, 0); \
            ACC[ct] = __builtin_amdgcn_mfma_f32_16x16x32_bf16(AH[kt], BH, ACC[ct], 0, 0, 0); \
        }

#define MFMA2(ACC)                                                               \
    _Pragma("unroll")                                                            \
    for (int ct = 0; ct < 4; ++ct)                                               \
        _Pragma("unroll")                                                        \
        for (int kt = 0; kt < 2; ++kt) {                                         \
            bf16x8 BH = __builtin_bit_cast(bf16x8, bh[ct][kt]);                  \
            bf16x8 BL = __builtin_bit_cast(bf16x8, bl[ct][kt]);                  \
            ACC[ct] = __builtin_amdgcn_mfma_f32_16x16x32_bf16(AH[kt], BL, ACC[ct], 0, 0, 0); \
            ACC[ct] = __builtin_amdgcn_mfma_f32_16x16x32_bf16(AH[kt], BH, ACC[ct], 0, 0, 0); \
        }

    float aggr[4] = { 0.f, 0.f, 0.f, 0.f };
    float swave = 0.f;

    for (int c = 0; c < 2; ++c) {
        const int T0 = c ? 7 : 0;     // first global tile of chunk
        const int NT = c ? 6 : 7;     // tiles in chunk
        if (c) __syncthreads();       // prev chunk's X fully consumed

        // ---- stage chunk rows: gather user_emb, hw-cvt split, swizzled LDS ----
        {
            const int dq = tid & 15;       // 4-col group
            const int rowt = tid >> 4;     // 0..15
            for (int p = 0; p < NT; ++p) {
                int lr = p * 16 + rowt;        // local row
                int n  = T0 * 16 + lr;         // global row
                int uid = 0, rid = 0;
                float4 v = make_float4(0.f, 0.f, 0.f, 0.f);
                if (n < N_SZ) {
                    int2 pr = ((const int2*)pad)[b * N_SZ + n];
                    uid = pr.x; rid = pr.y;
                    v = *(const float4*)(user_emb + (size_t)uid * 64 + dq * 4);
                }
                __bf16 h0 = (__bf16)v.x, h1 = (__bf16)v.y, h2 = (__bf16)v.z, h3 = (__bf16)v.w;
                bf16x4 hv = { h0, h1, h2, h3 };
                bf16x4 lv = { (__bf16)(v.x - (float)h0), (__bf16)(v.y - (float)h1),
                              (__bf16)(v.z - (float)h2), (__bf16)(v.w - (float)h3) };
                int g = dq >> 1;
                int idx = lr * 64 + ((g ^ (lr & 7)) << 3) + (dq & 1) * 4;
                *(bf16x4*)&XH[idx] = hv;
                *(bf16x4*)&XL[idx] = lv;
                if (dq == 0) {
                    rid_s[lr]  = (n < N_SZ) ? rid : 0;
                    mask_s[lr] = (n < N_SZ && uid > 0) ? 1.f : 0.f;
                }
            }
        }
        __syncthreads();

        f32x4 f_reg[2][4];   // this wave's layer-2 outputs (<=2 tiles/chunk)

        // ---- layer 1: h = relu(P @ W1a^T + erc[rid]) ----
        {
            LOAD_B(0)
#pragma unroll
            for (int ti = 0; ti < 2; ++ti) {
                int lt = w + 4 * ti;
                if (lt < NT) {
                    bf16x8 AH[2], AL[2];
                    loadA(XH, lt, AH);
                    loadA(XL, lt, AL);
                    int nr[4], ridr[4];
#pragma unroll
                    for (int r = 0; r < 4; ++r) { nr[r] = lt * 16 + lgrp * 4 + r; ridr[r] = rid_s[nr[r]]; }
                    f32x4 acc[4];
#pragma unroll
                    for (int ct = 0; ct < 4; ++ct) {
                        int k = ct * 16 + lcol;
#pragma unroll
                        for (int r = 0; r < 4; ++r) acc[ct][r] = erc_s[ridr[r] * 65 + k];
                    }
                    MFMA3(acc)
#pragma unroll
                    for (int ct = 0; ct < 4; ++ct) {
                        int col = ct * 16 + lcol;
#pragma unroll
                        for (int r = 0; r < 4; ++r) {
                            float hv = fmaxf(acc[ct][r], 0.f);
                            __bf16 hh = (__bf16)hv;
                            __bf16 ll = (__bf16)(hv - (float)hh);
                            int ln = nr[r];
                            int idx = ln * 64 + (((col >> 3) ^ (ln & 7)) << 3) + (col & 7);
                            XH[idx] = hh;
                            XL[idx] = ll;
                        }
                    }
                }
            }
        }
        asm volatile("s_waitcnt lgkmcnt(0)" ::: "memory");
        __builtin_amdgcn_sched_barrier(0);

        // ---- layer 2: f = h @ W2^T + b2 (kept in regs; hi stored for layer 3) ----
        {
            LOAD_B(1)
#pragma unroll
            for (int ti = 0; ti < 2; ++ti) {
                int lt = w + 4 * ti;
                if (lt < NT) {
                    bf16x8 AH[2], AL[2];
                    loadA(XH, lt, AH);
                    loadA(XL, lt, AL);
                    f32x4 (&acc)[4] = f_reg[ti];
#pragma unroll
                    for (int ct = 0; ct < 4; ++ct) {
                        float bb = b2_s[ct * 16 + lcol];
#pragma unroll
                        for (int r = 0; r < 4; ++r) acc[ct][r] = bb;
                    }
                    MFMA3(acc)
#pragma unroll
                    for (int ct = 0; ct < 4; ++ct) {
                        int col = ct * 16 + lcol;
#pragma unroll
                        for (int r = 0; r < 4; ++r) {
                            int ln = lt * 16 + lgrp * 4 + r;
                            int idx = ln * 64 + (((col >> 3) ^ (ln & 7)) << 3) + (col & 7);
                            XH[idx] = (__bf16)acc[ct][r];   // hi only — layer-3 A operand
                        }
                    }
                }
            }
        }
        asm volatile("s_waitcnt lgkmcnt(0)" ::: "memory");
        __builtin_amdgcn_sched_barrier(0);

        // ---- layer 3 + miu + in-register agg ----
        {
            LOAD_B(2)
#pragma unroll
            for (int ti = 0; ti < 2; ++ti) {
                int lt = w + 4 * ti;
                if (lt < NT) {
                    bf16x8 AH[2];
                    loadA(XH, lt, AH);
                    float maskr[4];
#pragma unroll
                    for (int r = 0; r < 4; ++r) maskr[r] = mask_s[lt * 16 + lgrp * 4 + r];
                    f32x4 acc[4];
#pragma unroll
                    for (int ct = 0; ct < 4; ++ct) {
                        int k = ct * 16 + lcol;
                        float bb = ab1_s[k], qq = qc_s[k];
#pragma unroll
                        for (int r = 0; r < 4; ++r) acc[ct][r] = fmaf(maskr[r], qq, bb);
                    }
                    MFMA2(acc)
                    float pm[4] = { 0.f, 0.f, 0.f, 0.f };
#pragma unroll
                    for (int ct = 0; ct < 4; ++ct) {
                        float w2v = aw2_s[ct * 16 + lcol];
#pragma unroll
                        for (int r = 0; r < 4; ++r)
                            pm[r] = fmaf(fmaxf(acc[ct][r], 0.f), w2v, pm[r]);
                    }
#pragma unroll
                    for (int off = 1; off <= 8; off <<= 1) {
#pragma unroll
                        for (int r = 0; r < 4; ++r) pm[r] += __shfl_xor(pm[r], off);
                    }
                    float miur[4];
#pragma unroll
                    for (int r = 0; r < 4; ++r) {
                        miur[r] = __expf(pm[r] + ab2) * maskr[r];
                        swave += miur[r];
                    }
#pragma unroll
                    for (int ct = 0; ct < 4; ++ct)
#pragma unroll
                        for (int r = 0; r < 4; ++r)
                            aggr[ct] = fmaf(miur[r], f_reg[ti][ct][r], aggr[ct]);
                }
            }
        }
    }

    // ---- cross-wave reduction (values uniform within 16-lane group) ----
#pragma unroll
    for (int ct = 0; ct < 4; ++ct) {
        float v = aggr[ct];
        v += __shfl_xor(v, 16);
        v += __shfl_xor(v, 32);
        aggr[ct] = v;
    }
    swave += __shfl_xor(swave, 16);
    swave += __shfl_xor(swave, 32);
    if (lane < 16) {
#pragma unroll
        for (int ct = 0; ct < 4; ++ct) aggp[w][ct * 16 + lane] = aggr[ct];
    }
    if (lane == 0) red_s[w] = swave;
    __syncthreads();

    const float inv = 1.f / (red_s[0] + red_s[1] + red_s[2] + red_s[3] + 1e-10f);
    if (tid < 64)
        agg_s[tid] = (aggp[0][tid] + aggp[1][tid] + aggp[2][tid] + aggp[3][tid]) * inv;
    __syncthreads();

    // ---- z = relu(agg @ agg_w^T + agg_b) ----
    if (tid < 64) {
        const int k = tid;
        float z = agg_b[k];
        const float4* wr = (const float4*)(agg_w + k * 64);
#pragma unroll
        for (int i = 0; i < 16; ++i) {
            float4 wv = wr[i];
            z = fmaf(wv.x, agg_s[4 * i + 0], z);
            z = fmaf(wv.y, agg_s[4 * i + 1], z);
            z = fmaf(wv.z, agg_s[4 * i + 2], z);
            z = fmaf(wv.w, agg_s[4 * i + 3], z);
        }
        out[b * 64 + k] = fmaxf(z, 0.f);
    }
}

extern "C" void kernel_launch(void* const* d_in, const int* in_sizes, int n_in,
                              void* d_out, int out_size, void* d_ws, size_t ws_size,
                              hipStream_t stream) {
    const int*   iids     = (const int*)d_in[0];
    const int*   pad      = (const int*)d_in[1];
    const float* user_emb = (const float*)d_in[2];
    const float* item_emb = (const float*)d_in[3];
    const float* rate_emb = (const float*)d_in[4];
    const float* gu_w1    = (const float*)d_in[5];
    const float* gu_b1    = (const float*)d_in[6];
    const float* gu_w2    = (const float*)d_in[7];
    const float* gu_b2    = (const float*)d_in[8];
    const float* att_w1   = (const float*)d_in[9];
    const float* att_b1   = (const float*)d_in[10];
    const float* att_w2   = (const float*)d_in[11];
    const float* att_b2   = (const float*)d_in[12];
    const float* agg_w    = (const float*)d_in[13];
    const float* agg_b    = (const float*)d_in[14];
    float* ws  = (float*)d_ws;
    float* out = (float*)d_out;

    hipLaunchKernelGGL(prep1, dim3(1), dim3(256), 0, stream,
                       gu_w1, gu_b1, gu_w2, att_w1, rate_emb, ws);
    hipLaunchKernelGGL(prep2_qc, dim3(B_SZ), dim3(64), 0, stream,
                       iids, item_emb, ws, ws + OFF_QC);
    hipLaunchKernelGGL(fused_main, dim3(B_SZ), dim3(256), 0, stream,
                       pad, user_emb, gu_b2, att_b1, att_w2, att_b2, agg_w, agg_b, ws, out);
}

// Round 6
// 212.961 us; speedup vs baseline: 4.0437x; 4.0437x over previous
//
#include <hip/hip_runtime.h>
#include <hip/hip_bf16.h>

#define B_SZ 4096
#define N_SZ 200

// workspace offsets (4-byte units)
#define OFF_BFRAG 0        // 12288 u32: B-fragments, 3 layers x 2kt x 4ct x 2(hi/lo) x 64 lanes x 4 u32
#define OFF_AW1BT 12288    // 4096 f32: aw1bT[d][k] = att_w1[k][64+d]  (for qc prep)
#define OFF_ERC   16384    // 384  f32: erc[r][k]
#define OFF_QC    16768    // B*64 f32: qc[b][k]

typedef __attribute__((ext_vector_type(8))) __bf16 bf16x8;
typedef __attribute__((ext_vector_type(4))) __bf16 bf16x4;
typedef __attribute__((ext_vector_type(4))) float f32x4;
typedef __attribute__((ext_vector_type(4))) unsigned u32x4;

__device__ __forceinline__ void split2(float x, unsigned &hi, unsigned &lo) {
    unsigned u = __float_as_uint(x);
    hi = (u + 0x7FFFu + ((u >> 16) & 1u)) >> 16;
    float r = x - __uint_as_float(hi << 16);
    unsigned ul = __float_as_uint(r);
    lo = (ul + 0x7FFFu + ((ul >> 16) & 1u)) >> 16;
}

// ---------- prep ----------
__global__ void prep1(const float* __restrict__ gu_w1, const float* __restrict__ gu_b1,
                      const float* __restrict__ gu_w2, const float* __restrict__ att_w1,
                      const float* __restrict__ rate_emb, float* __restrict__ ws) {
    int t = threadIdx.x;  // 1 block x 256
    unsigned* wsu = (unsigned*)ws;
    for (int i = t; i < 12288; i += 256) {
        int frag = i >> 8, within = i & 255, lane = within >> 2, r = within & 3;
        int hl = frag & 1, ct = (frag >> 1) & 3, kt = (frag >> 3) & 1, layer = frag >> 4;
        int col = ct * 16 + (lane & 15);
        int d0 = kt * 32 + 8 * (lane >> 4) + 2 * r;
        float w0, w1v;
        if (layer == 0)      { w0 = gu_w1[col * 128 + d0];  w1v = gu_w1[col * 128 + d0 + 1]; }
        else if (layer == 1) { w0 = gu_w2[col * 64 + d0];   w1v = gu_w2[col * 64 + d0 + 1]; }
        else                 { w0 = att_w1[col * 128 + d0]; w1v = att_w1[col * 128 + d0 + 1]; }
        unsigned h0, l0, h1, l1;
        split2(w0, h0, l0); split2(w1v, h1, l1);
        unsigned lo16 = hl ? l0 : h0;
        unsigned hi16 = hl ? l1 : h1;
        wsu[OFF_BFRAG + i] = lo16 | (hi16 << 16);
    }
    for (int i = t; i < 4096; i += 256) {
        int d = i >> 6, k = i & 63;
        ws[OFF_AW1BT + i] = att_w1[k * 128 + 64 + d];
    }
    for (int i = t; i < 384; i += 256) {
        int rr = i >> 6, k = i & 63;
        float a = gu_b1[k];
        for (int d = 0; d < 64; ++d)
            a += gu_w1[k * 128 + 64 + d] * rate_emb[rr * 64 + d];
        ws[OFF_ERC + i] = a;
    }
}

__global__ void prep2_qc(const int* __restrict__ iids, const float* __restrict__ item_emb,
                         const float* __restrict__ ws, float* __restrict__ qc) {
    int b = blockIdx.x, k = threadIdx.x;
    int iid = iids[b];
    const float* awbT = ws + OFF_AW1BT;
    const float* irow = item_emb + (size_t)iid * 64;
    float acc = 0.f;
    for (int d = 0; d < 64; ++d)
        acc = fmaf(awbT[d * 64 + k], irow[d], acc);
    qc[b * 64 + k] = acc;
}

// ---------- fused main: 512 threads (8 waves), single 208-row chunk ----------
__global__ __launch_bounds__(512, 2) void fused_main(
    const int* __restrict__ pad, const float* __restrict__ user_emb,
    const float* __restrict__ gu_b2, const float* __restrict__ att_b1,
    const float* __restrict__ att_w2, const float* __restrict__ att_b2,
    const float* __restrict__ agg_w, const float* __restrict__ agg_b,
    const float* __restrict__ ws, float* __restrict__ out) {

    // hi/lo activation planes: 208 rows x 64 cols bf16.
    // 16B granule g (8 cols) of row n stored at granule (g ^ (n&7)).
    __shared__ __align__(16) __bf16 XH[208 * 64];
    __shared__ __align__(16) __bf16 XL[208 * 64];
    __shared__ float erc_s[6 * 65];
    __shared__ int   rid_s[208];
    __shared__ float mask_s[208];
    __shared__ float b2_s[64], aw2_s[64], ab1_s[64], qc_s[64];
    __shared__ float aggp[8][64];
    __shared__ float agg_s[64];
    __shared__ float red_s[8];

    const int b = blockIdx.x;
    const int tid = threadIdx.x;
    const int w = tid >> 6;        // wave 0..7
    const int lane = tid & 63;
    const int lrow = lane & 15;
    const int lgrp = lane >> 4;
    const int lcol = lane & 15;
    const unsigned* __restrict__ bfrag = (const unsigned*)ws + OFF_BFRAG;
    const float ab2 = att_b2[0];

    // ---- stage: gather user_emb rows, hw-cvt split to hi/lo planes ----
    {
        const int dq = tid & 15;       // 4-col group
        const int rowt = tid >> 4;     // 0..31
        for (int p = 0; p < 7; ++p) {
            int lr = p * 32 + rowt;        // 0..223
            if (lr < 208) {
                int uid = 0, rid = 0;
                float4 v = make_float4(0.f, 0.f, 0.f, 0.f);
                if (lr < N_SZ) {
                    int2 pr = ((const int2*)pad)[b * N_SZ + lr];
                    uid = pr.x; rid = pr.y;
                    v = *(const float4*)(user_emb + (size_t)uid * 64 + dq * 4);
                }
                __bf16 h0 = (__bf16)v.x, h1 = (__bf16)v.y, h2 = (__bf16)v.z, h3 = (__bf16)v.w;
                bf16x4 hv = { h0, h1, h2, h3 };
                bf16x4 lv = { (__bf16)(v.x - (float)h0), (__bf16)(v.y - (float)h1),
                              (__bf16)(v.z - (float)h2), (__bf16)(v.w - (float)h3) };
                int g = dq >> 1;
                int idx = lr * 64 + ((g ^ (lr & 7)) << 3) + (dq & 1) * 4;
                *(bf16x4*)&XH[idx] = hv;
                *(bf16x4*)&XL[idx] = lv;
                if (dq == 0) {
                    rid_s[lr]  = (lr < N_SZ) ? rid : 0;
                    mask_s[lr] = (lr < N_SZ && uid > 0) ? 1.f : 0.f;
                }
            }
        }
        if (tid < 64) {
            b2_s[tid]  = gu_b2[tid];
            aw2_s[tid] = att_w2[tid];
            ab1_s[tid] = att_b1[tid];
            qc_s[tid]  = ws[OFF_QC + b * 64 + tid];
        }
        for (int i = tid; i < 384; i += 512)
            erc_s[(i >> 6) * 65 + (i & 63)] = ws[OFF_ERC + i];
    }
    __syncthreads();

    // A-frag: row n = lt*16+lrow, k = kt*32+8*lgrp+e -> exactly one swizzled granule
    auto loadA = [&](const __bf16* P, int lt, bf16x8 A[2]) {
        int n = lt * 16 + lrow;
        int s = n & 7;
#pragma unroll
        for (int kt = 0; kt < 2; ++kt)
            A[kt] = *(const bf16x8*)&P[n * 64 + (((kt * 4 + lgrp) ^ s) << 3)];
    };

#define LOAD_B(LAYER)                                                            \
    u32x4 bh[4][2], bl[4][2];                                                    \
    _Pragma("unroll")                                                            \
    for (int ct = 0; ct < 4; ++ct)                                               \
        _Pragma("unroll")                                                        \
        for (int kt = 0; kt < 2; ++kt) {                                         \
            int fb = (((LAYER) * 2 + kt) * 4 + ct) * 2;                          \
            bh[ct][kt] = *(const u32x4*)&bfrag[(fb + 0) * 256 + lane * 4];       \
            bl[ct][kt] = *(const u32x4*)&bfrag[(fb + 1) * 256 + lane * 4];       \
        }

#define MFMA3(ACC)                                                               \
    _Pragma("unroll")                                                            \
    for (int ct = 0; ct < 4; ++ct)                                               \
        _Pragma("unroll")                                                        \
        for (int kt = 0; kt < 2; ++kt) {                                         \
            bf16x8 BH = __builtin_bit_cast(bf16x8, bh[ct][kt]);                  \
            bf16x8 BL = __builtin_bit_cast(bf16x8, bl[ct][kt]);                  \
            ACC[ct] = __builtin_amdgcn_mfma_f32_16x16x32_bf16(AL[kt], BH, ACC[ct], 0, 0, 0); \
            ACC[ct] = __builtin_amdgcn_mfma_f32_16x16x32_bf16(AH[kt], BL, ACC[ct], 0, 0, 0); \
            ACC[ct] = __builtin_amdgcn_mfma_f32_16x16x32_bf16(AH[kt], BH, ACC[ct], 0, 0, 0); \
        }

#define MFMA2(ACC)                                                               \
    _Pragma("unroll")                                                            \
    for (int ct = 0; ct < 4; ++ct)                                               \
        _Pragma("unroll")                                                        \
        for (int kt = 0; kt < 2; ++kt) {                                         \
            bf16x8 BH = __builtin_bit_cast(bf16x8, bh[ct][kt]);                  \
            bf16x8 BL = __builtin_bit_cast(bf16x8, bl[ct][kt]);                  \
            ACC[ct] = __builtin_amdgcn_mfma_f32_16x16x32_bf16(AH[kt], BL, ACC[ct], 0, 0, 0); \
            ACC[ct] = __builtin_amdgcn_mfma_f32_16x16x32_bf16(AH[kt], BH, ACC[ct], 0, 0, 0); \
        }

    f32x4 f_reg[2][4];   // [tile ti][ct] — layer-2 outputs, kept exact for agg

    // ---- layer 1: h = relu(P @ W1a^T + erc[rid]) ----
    {
        LOAD_B(0)
#pragma unroll
        for (int ti = 0; ti < 2; ++ti) {
            int lt = w + 8 * ti;
            if (lt < 13) {
                bf16x8 AH[2], AL[2];
                loadA(XH, lt, AH);
                loadA(XL, lt, AL);
                int nr[4], ridr[4];
#pragma unroll
                for (int r = 0; r < 4; ++r) { nr[r] = lt * 16 + lgrp * 4 + r; ridr[r] = rid_s[nr[r]]; }
                f32x4 acc[4];
#pragma unroll
                for (int ct = 0; ct < 4; ++ct) {
                    int k = ct * 16 + lcol;
#pragma unroll
                    for (int r = 0; r < 4; ++r) acc[ct][r] = erc_s[ridr[r] * 65 + k];
                }
                MFMA3(acc)
#pragma unroll
                for (int ct = 0; ct < 4; ++ct) {
                    int col = ct * 16 + lcol;
#pragma unroll
                    for (int r = 0; r < 4; ++r) {
                        float hv = fmaxf(acc[ct][r], 0.f);
                        __bf16 hh = (__bf16)hv;
                        __bf16 ll = (__bf16)(hv - (float)hh);
                        int n = nr[r];
                        int idx = n * 64 + (((col >> 3) ^ (n & 7)) << 3) + (col & 7);
                        XH[idx] = hh;
                        XL[idx] = ll;
                    }
                }
            }
        }
    }
    // no fence: tiles are wave-private across layers; DS ops per wave are in-order,
    // and the compiler inserts use-waits for C++-level LDS reads.

    // ---- layer 2: f = h @ W2^T + b2 (kept in regs; hi stored for layer 3) ----
    {
        LOAD_B(1)
#pragma unroll
        for (int ti = 0; ti < 2; ++ti) {
            int lt = w + 8 * ti;
            if (lt < 13) {
                bf16x8 AH[2], AL[2];
                loadA(XH, lt, AH);
                loadA(XL, lt, AL);
                f32x4 (&acc)[4] = f_reg[ti];
#pragma unroll
                for (int ct = 0; ct < 4; ++ct) {
                    float bb = b2_s[ct * 16 + lcol];
#pragma unroll
                    for (int r = 0; r < 4; ++r) acc[ct][r] = bb;
                }
                MFMA3(acc)
#pragma unroll
                for (int ct = 0; ct < 4; ++ct) {
                    int col = ct * 16 + lcol;
#pragma unroll
                    for (int r = 0; r < 4; ++r) {
                        int n = lt * 16 + lgrp * 4 + r;
                        int idx = n * 64 + (((col >> 3) ^ (n & 7)) << 3) + (col & 7);
                        XH[idx] = (__bf16)acc[ct][r];   // hi only — layer-3 A operand
                    }
                }
            }
        }
    }

    // ---- layer 3 + miu + in-register agg ----
    float aggr[4] = { 0.f, 0.f, 0.f, 0.f };
    float swave = 0.f;
    {
        LOAD_B(2)
#pragma unroll
        for (int ti = 0; ti < 2; ++ti) {
            int lt = w + 8 * ti;
            if (lt < 13) {
                bf16x8 AH[2];
                loadA(XH, lt, AH);
                float maskr[4];
#pragma unroll
                for (int r = 0; r < 4; ++r) maskr[r] = mask_s[lt * 16 + lgrp * 4 + r];
                f32x4 acc[4];
#pragma unroll
                for (int ct = 0; ct < 4; ++ct) {
                    int k = ct * 16 + lcol;
                    float bb = ab1_s[k], qq = qc_s[k];
#pragma unroll
                    for (int r = 0; r < 4; ++r) acc[ct][r] = fmaf(maskr[r], qq, bb);
                }
                MFMA2(acc)
                float pm[4] = { 0.f, 0.f, 0.f, 0.f };
#pragma unroll
                for (int ct = 0; ct < 4; ++ct) {
                    float w2v = aw2_s[ct * 16 + lcol];
#pragma unroll
                    for (int r = 0; r < 4; ++r)
                        pm[r] = fmaf(fmaxf(acc[ct][r], 0.f), w2v, pm[r]);
                }
#pragma unroll
                for (int off = 1; off <= 8; off <<= 1) {
#pragma unroll
                    for (int r = 0; r < 4; ++r) pm[r] += __shfl_xor(pm[r], off);
                }
                float miur[4];
#pragma unroll
                for (int r = 0; r < 4; ++r) {
                    miur[r] = __expf(pm[r] + ab2) * maskr[r];
                    swave += miur[r];
                }
#pragma unroll
                for (int ct = 0; ct < 4; ++ct)
#pragma unroll
                    for (int r = 0; r < 4; ++r)
                        aggr[ct] = fmaf(miur[r], f_reg[ti][ct][r], aggr[ct]);
            }
        }
    }

    // ---- cross-wave reduction (values uniform within 16-lane group) ----
#pragma unroll
    for (int ct = 0; ct < 4; ++ct) {
        float v = aggr[ct];
        v += __shfl_xor(v, 16);
        v += __shfl_xor(v, 32);
        aggr[ct] = v;
    }
    swave += __shfl_xor(swave, 16);
    swave += __shfl_xor(swave, 32);
    if (lane < 16) {
#pragma unroll
        for (int ct = 0; ct < 4; ++ct) aggp[w][ct * 16 + lane] = aggr[ct];
    }
    if (lane == 0) red_s[w] = swave;
    __syncthreads();

    const float inv = 1.f / (red_s[0] + red_s[1] + red_s[2] + red_s[3] +
                             red_s[4] + red_s[5] + red_s[6] + red_s[7] + 1e-10f);
    if (tid < 64) {
        float a = 0.f;
#pragma unroll
        for (int q = 0; q < 8; ++q) a += aggp[q][tid];
        agg_s[tid] = a * inv;
    }
    __syncthreads();

    // ---- z = relu(agg @ agg_w^T + agg_b) ----
    if (tid < 64) {
        const int k = tid;
        float z = agg_b[k];
        const float4* wr = (const float4*)(agg_w + k * 64);
#pragma unroll
        for (int i = 0; i < 16; ++i) {
            float4 wv = wr[i];
            z = fmaf(wv.x, agg_s[4 * i + 0], z);
            z = fmaf(wv.y, agg_s[4 * i + 1], z);
            z = fmaf(wv.z, agg_s[4 * i + 2], z);
            z = fmaf(wv.w, agg_s[4 * i + 3], z);
        }
        out[b * 64 + k] = fmaxf(z, 0.f);
    }
}

extern "C" void kernel_launch(void* const* d_in, const int* in_sizes, int n_in,
                              void* d_out, int out_size, void* d_ws, size_t ws_size,
                              hipStream_t stream) {
    const int*   iids     = (const int*)d_in[0];
    const int*   pad      = (const int*)d_in[1];
    const float* user_emb = (const float*)d_in[2];
    const float* item_emb = (const float*)d_in[3];
    const float* rate_emb = (const float*)d_in[4];
    const float* gu_w1    = (const float*)d_in[5];
    const float* gu_b1    = (const float*)d_in[6];
    const float* gu_w2    = (const float*)d_in[7];
    const float* gu_b2    = (const float*)d_in[8];
    const float* att_w1   = (const float*)d_in[9];
    const float* att_b1   = (const float*)d_in[10];
    const float* att_w2   = (const float*)d_in[11];
    const float* att_b2   = (const float*)d_in[12];
    const float* agg_w    = (const float*)d_in[13];
    const float* agg_b    = (const float*)d_in[14];
    float* ws  = (float*)d_ws;
    float* out = (float*)d_out;

    hipLaunchKernelGGL(prep1, dim3(1), dim3(256), 0, stream,
                       gu_w1, gu_b1, gu_w2, att_w1, rate_emb, ws);
    hipLaunchKernelGGL(prep2_qc, dim3(B_SZ), dim3(64), 0, stream,
                       iids, item_emb, ws, ws + OFF_QC);
    hipLaunchKernelGGL(fused_main, dim3(B_SZ), dim3(512), 0, stream,
                       pad, user_emb, gu_b2, att_b1, att_w2, att_b2, agg_w, agg_b, ws, out);
}